// Round 6
// baseline (264.428 us; speedup 1.0000x reference)
//
#include <hip/hip_runtime.h>
#include <math.h>

#define CUTOFF   513
#define NFRAMES  4095
#define TLEN     2097152
#define NBATCH   16
#define NW       4   // waves per block; each wave: one packed pair-FFT (2 frames)
#define MTS      9   // mag-tile row stride (odd -> conflict-free with u=lane map)

// compiler barrier + drain this wave's LDS ops (FFT phase is wave-private)
#define WAVE_SYNC() asm volatile("s_waitcnt lgkmcnt(0)" ::: "memory")

// complex number in a VGPR pair: .x = real (lo), .y = imag (hi)
typedef float cplx __attribute__((ext_vector_type(2)));

// ---- packed fp32 complex primitives (VOP3P: 1-2 insts instead of 2-4 scalar)
__device__ __forceinline__ cplx cadd(cplx a, cplx b){
    cplx r; asm("v_pk_add_f32 %0, %1, %2" : "=v"(r) : "v"(a), "v"(b)); return r;
}
__device__ __forceinline__ cplx csub(cplx a, cplx b){
    cplx r; asm("v_pk_add_f32 %0, %1, %2 op_sel:[0,0] op_sel_hi:[1,1] neg_lo:[0,1] neg_hi:[0,1]"
                : "=v"(r) : "v"(a), "v"(b)); return r;
}
// a - i*b = (a.x + b.y, a.y - b.x)
__device__ __forceinline__ cplx submul_i(cplx a, cplx b){
    cplx r; asm("v_pk_add_f32 %0, %1, %2 op_sel:[0,1] op_sel_hi:[1,0] neg_hi:[0,1]"
                : "=v"(r) : "v"(a), "v"(b)); return r;
}
// a + i*b = (a.x - b.y, a.y + b.x)
__device__ __forceinline__ cplx addmul_i(cplx a, cplx b){
    cplx r; asm("v_pk_add_f32 %0, %1, %2 op_sel:[0,1] op_sel_hi:[1,0] neg_lo:[0,1]"
                : "=v"(r) : "v"(a), "v"(b)); return r;
}
// full complex multiply: (ax*bx - ay*by, ax*by + ay*bx), 2 packed insts
__device__ __forceinline__ cplx cmul(cplx a, cplx b){
    cplx t, r;
    asm("v_pk_mul_f32 %0, %1, %2 op_sel:[1,1] op_sel_hi:[1,0]"
        : "=v"(t) : "v"(a), "v"(b));                       // (ay*by, ay*bx)
    asm("v_pk_fma_f32 %0, %1, %2, %3 op_sel:[0,0,0] op_sel_hi:[0,1,1] neg_lo:[0,0,1]"
        : "=v"(r) : "v"(a), "v"(b), "v"(t));               // (ax*bx - ay*by, ax*by + ay*bx)
    return r;
}
__device__ __forceinline__ cplx cmul_mi(cplx a){ return (cplx){a.y, -a.x}; }  // *(-i)

// raw v_sqrt_f32 (1 inst; ~1-2 ulp, fine under 0.5-abs tolerance)
__device__ __forceinline__ float fsqrt(float x){
    float r; asm("v_sqrt_f32 %0, %1" : "=v"(r) : "v"(x)); return r;
}

// natural-order in/out 16-point DFT (W16 = e^{-2pi i/16}), fully in registers
__device__ __forceinline__ void fft16(cplx* A) {
    const float C1 = 0.92387953251f, S1 = 0.38268343236f, HF = 0.70710678119f;
    cplx C[16];
    #pragma unroll
    for (int j4 = 0; j4 < 4; ++j4) {
        cplx a = A[j4], b = A[j4+4], c = A[j4+8], d = A[j4+12];
        cplx t0 = cadd(a,c), t1 = csub(a,c), t2 = cadd(b,d), t3 = csub(b,d);
        C[4*j4+0] = cadd(t0,t2);
        C[4*j4+1] = submul_i(t1,t3);
        C[4*j4+2] = csub(t0,t2);
        C[4*j4+3] = addmul_i(t1,t3);
    }
    // twiddle C[j4][klo] *= W16^{j4*klo}
    C[4*1+1] = cmul(C[4*1+1], (cplx){ C1,-S1});
    C[4*1+2] = cmul(C[4*1+2], (cplx){ HF,-HF});
    C[4*1+3] = cmul(C[4*1+3], (cplx){ S1,-C1});
    C[4*2+1] = cmul(C[4*2+1], (cplx){ HF,-HF});
    C[4*2+2] = cmul_mi(C[4*2+2]);                             // W16^4 = -i
    C[4*2+3] = cmul(C[4*2+3], (cplx){-HF,-HF});
    C[4*3+1] = cmul(C[4*3+1], (cplx){ S1,-C1});
    C[4*3+2] = cmul(C[4*3+2], (cplx){-HF,-HF});
    C[4*3+3] = cmul(C[4*3+3], (cplx){-C1, S1});               // W16^9
    #pragma unroll
    for (int klo = 0; klo < 4; ++klo) {
        cplx a = C[klo], b = C[4+klo], c = C[8+klo], d = C[12+klo];
        cplx t0 = cadd(a,c), t1 = csub(a,c), t2 = cadd(b,d), t3 = csub(b,d);
        A[klo]    = cadd(t0,t2);
        A[klo+4]  = submul_i(t1,t3);
        A[klo+8]  = csub(t0,t2);
        A[klo+12] = addmul_i(t1,t3);
    }
}

// X[k3] = sum_{j2} h[j2] W4^{j2 k3}
__device__ __forceinline__ void dft4(const cplx* h, cplx* X) {
    cplx t0 = cadd(h[0],h[2]), t1 = csub(h[0],h[2]);
    cplx t2 = cadd(h[1],h[3]), t3 = csub(h[1],h[3]);
    X[0] = cadd(t0,t2);
    X[1] = submul_i(t1,t3);
    X[2] = csub(t0,t2);
    X[3] = addmul_i(t1,t3);
}

// Hermitian unpack of packed pair at (Z_k, Z_{1024-k}) -> (|A_k|, |B_k|)
__device__ __forceinline__ float2 magpair(cplx Zk, cplx Zm) {
    cplx xs, ys, s;
    asm("v_pk_add_f32 %0, %1, %2 op_sel:[0,0] op_sel_hi:[0,0] neg_hi:[0,1]"
        : "=v"(xs) : "v"(Zk), "v"(Zm));     // (Zk.x+Zm.x, Zk.x-Zm.x)
    asm("v_pk_add_f32 %0, %1, %2 op_sel:[1,1] op_sel_hi:[1,1] neg_lo:[0,1]"
        : "=v"(ys) : "v"(Zk), "v"(Zm));     // (Zk.y-Zm.y, Zk.y+Zm.y)
    asm("v_pk_mul_f32 %0, %1, %1" : "=v"(s) : "v"(xs));
    asm("v_pk_fma_f32 %0, %1, %1, %2" : "=v"(s) : "v"(ys), "v"(s));
    return make_float2(0.5f*fsqrt(s.x), 0.5f*fsqrt(s.y));
}

__global__ __launch_bounds__(256, 5)
void stft_mag_kernel(const float* __restrict__ in, float* __restrict__ out,
                     const cplx* __restrict__ twg) {
    // 32 KB total: FFT workspace, later aliased as 513 x 8 mag tile (stride 9).
    __shared__ __align__(16) cplx fftb[NW][1024];
    float* mt = (float*)fftb;   // alias: valid after all waves finish readout
    const int tid = threadIdx.x, lane = tid & 63, w = tid >> 6;
    // XCD swizzle: xcd (H&7) owns a contiguous 1024-block chunk -> line-sharing
    // neighbor blocks co-reside on one XCD's L2; output writes merge pre-HBM.
    const int H = blockIdx.x;
    const int LB = ((H & 7) << 10) | (H >> 3);
    const int b = LB >> 9, blk = LB & 511;
    const int p = 4 * blk + w;                 // pair 0..2047 -> frames 2p, 2p+1
    const bool noB = (2 * p + 1) >= NFRAMES;   // only pair 2047
    const float* bi = in + (size_t)b * TLEN;
    float* bo = out + (size_t)b * ((size_t)CUTOFF * NFRAMES);
    cplx* buf = fftb[w];

    // ---- load: lane j holds x[64r + j]; z = frameA + i*frameB
    float v[24];
    const float* src = bi + 1024 * p + lane;
    #pragma unroll
    for (int t = 0; t < 16; ++t) v[t] = src[64 * t];
    #pragma unroll
    for (int t = 16; t < 24; ++t) v[t] = noB ? 0.f : src[64 * t];
    // T1 twiddle table loads (L1/L2-resident; latency hides under fft16)
    cplx tw1[15];
    #pragma unroll
    for (int k = 0; k < 15; ++k) tw1[k] = twg[64 * k + lane];
    cplx A[16];
    #pragma unroll
    for (int r = 0; r < 16; ++r) A[r] = (cplx){v[r], noB ? 0.f : v[r + 8]};

    // ---- stage A: FFT-16 over r, then T1 twiddle W1024^{lane*k1} (from table)
    fft16(A);
    #pragma unroll
    for (int k = 1; k < 16; ++k) A[k] = cmul(A[k], tw1[k - 1]);
    // transpose 1: addr(k1, j) = 64*k1 + ((j + 4*k1) & 63)
    #pragma unroll
    for (int k = 0; k < 16; ++k)
        buf[64 * k + ((lane + 4 * k) & 63)] = A[k];
    // T2 twiddle loads: overlap with stage-B LDS reads + fft16
    cplx tw2[15];
    #pragma unroll
    for (int k = 0; k < 15; ++k) tw2[k] = twg[960 + 64 * k + lane];
    WAVE_SYNC();

    // ---- stage B: lane = (k1 = lane&15, j2 = lane>>4); FFT-16; T2 W64^{j2*k2}
    const int k1 = lane & 15, j2 = lane >> 4;
    #pragma unroll
    for (int r = 0; r < 16; ++r)
        A[r] = buf[64 * k1 + ((4 * r + j2 + 4 * k1) & 63)];
    fft16(A);
    #pragma unroll
    for (int k = 1; k < 16; ++k) A[k] = cmul(A[k], tw2[k - 1]);
    WAVE_SYNC();   // all lanes' stage-B reads drained before in-place overwrite
    // transpose 2: quartet q = k1+16*k2 at float2 base 4*sq, sq = q^(q>>4).
    // Half-swap swizzle e = bit2(sq): halves at 32*sq + 16*(half^e) -> b128
    // readout quad-index (2*sq+e)&7 uniform over lanes -> conflict-free.
    #pragma unroll
    for (int k = 0; k < 16; ++k) {
        int sv = k1 ^ k;                 // low 4 bits of sq (k2 = k)
        int eo = (sv >> 2) & 1;
        buf[64 * k + 4 * sv + 2 * ((j2 >> 1) ^ eo) + (j2 & 1)] = A[k];
    }
    WAVE_SYNC();

    // ---- readout: 128 units; lane handles u = lane, lane+64 (bijection; this
    // mapping makes the later stride-9 mt writes conflict-free: 9*lane mod 32
    // spans all banks, 2 lanes/bank).
    const int f0 = 2 * w;   // block-local frames: f0 (A), f0+1 (B)
    const float4* q4 = (const float4*)buf;
    float ch[16], m512a = 0.f, m512b = 0.f;
    #pragma unroll
    for (int vv = 0; vv < 2; ++vv) {
        const int u = lane + 64 * vv;
        if (u == 0) {
            float4 a0 = q4[0], a1 = q4[1];           // sq=0, e=0
            float4 b0 = q4[272], b1 = q4[273];       // q=128: sq=136, e=0
            cplx hq[4], hp[4];
            hq[0]=(cplx){a0.x,a0.y}; hq[1]=(cplx){a0.z,a0.w}; hq[2]=(cplx){a1.x,a1.y}; hq[3]=(cplx){a1.z,a1.w};
            hp[0]=(cplx){b0.x,b0.y}; hp[1]=(cplx){b0.z,b0.w}; hp[2]=(cplx){b1.x,b1.y}; hp[3]=(cplx){b1.z,b1.w};
            cplx X0[4], X1[4];
            dft4(hq, X0); dft4(hp, X1);
            ch[0] = fabsf(X0[0].x); ch[1] = fabsf(X0[0].y);               // row 0
            float2 m = magpair(X0[1], X0[3]); ch[2] = m.x; ch[3] = m.y;   // row 256
            m = magpair(X1[0], X1[3]); ch[4] = m.x; ch[5] = m.y;          // row 128
            m = magpair(X1[1], X1[2]); ch[6] = m.x; ch[7] = m.y;          // row 384
            m512a = fabsf(X0[2].x); m512b = fabsf(X0[2].y);               // row 512
        } else {
            const int q = u, qp = 256 - u;
            const int sq = q ^ (q >> 4), sp = qp ^ (qp >> 4);
            const int eq = (sq >> 2) & 1,  ep = (sp >> 2) & 1;
            float4 a0 = q4[2*sq + eq], a1 = q4[2*sq + 1 - eq];
            float4 b0 = q4[2*sp + ep], b1 = q4[2*sp + 1 - ep];
            cplx hq[4], hp[4];
            hq[0]=(cplx){a0.x,a0.y}; hq[1]=(cplx){a0.z,a0.w}; hq[2]=(cplx){a1.x,a1.y}; hq[3]=(cplx){a1.z,a1.w};
            hp[0]=(cplx){b0.x,b0.y}; hp[1]=(cplx){b0.z,b0.w}; hp[2]=(cplx){b1.x,b1.y}; hp[3]=(cplx){b1.z,b1.w};
            cplx Xq[4], Xp[4];
            dft4(hq, Xq); dft4(hp, Xp);
            float2 m;
            m = magpair(Xq[0], Xp[3]); ch[8*vv+0] = m.x; ch[8*vv+1] = m.y;  // row u
            m = magpair(Xq[1], Xp[2]); ch[8*vv+2] = m.x; ch[8*vv+3] = m.y;  // row u+256
            m = magpair(Xp[0], Xq[3]); ch[8*vv+4] = m.x; ch[8*vv+5] = m.y;  // row 256-u
            m = magpair(Xp[1], Xq[2]); ch[8*vv+6] = m.x; ch[8*vv+7] = m.y;  // row 512-u
        }
    }
    __syncthreads();   // all waves done with fftb -> mt may alias it

    // ---- mag-tile writes (513 rows x 8 frames, row stride 9)
    auto MTW = [&](int k, int f, float val) { mt[MTS * k + f] = val; };
    #pragma unroll
    for (int vv = 0; vv < 2; ++vv) {
        const int u = lane + 64 * vv;
        if (u == 0) {
            MTW(0,   f0, ch[0]); MTW(0,   f0 + 1, ch[1]);
            MTW(256, f0, ch[2]); MTW(256, f0 + 1, ch[3]);
            MTW(128, f0, ch[4]); MTW(128, f0 + 1, ch[5]);
            MTW(384, f0, ch[6]); MTW(384, f0 + 1, ch[7]);
            MTW(512, f0, m512a); MTW(512, f0 + 1, m512b);
        } else {
            MTW(u,       f0, ch[8*vv+0]); MTW(u,       f0+1, ch[8*vv+1]);
            MTW(u + 256, f0, ch[8*vv+2]); MTW(u + 256, f0+1, ch[8*vv+3]);
            MTW(256 - u, f0, ch[8*vv+4]); MTW(256 - u, f0+1, ch[8*vv+5]);
            MTW(512 - u, f0, ch[8*vv+6]); MTW(512 - u, f0+1, ch[8*vv+7]);
        }
    }
    __syncthreads();

    // ---- flush: rows c=0..512, 8 frames/row (32B runs)
    #pragma unroll
    for (int i = 0; i < 17; ++i) {
        int L = 256 * i + tid;
        if (L < 513 * 8) {
            int c = L >> 3, f = L & 7;
            int n = 8 * blk + f;
            if (n < NFRAMES)
                bo[(size_t)c * NFRAMES + n] = mt[MTS * c + f];
        }
    }
}

extern "C" void kernel_launch(void* const* d_in, const int* in_sizes, int n_in,
                              void* d_out, int out_size, void* d_ws, size_t ws_size,
                              hipStream_t stream) {
    const float* in = (const float*)d_in[0];   // (16, 2097152) fp32
    float* out = (float*)d_out;                // (16, 513, 4095) fp32
    // Twiddle table: [15][64] W1024^{lane*k} then [15][64] W64^{(lane>>4)*k}
    static float host_tw[1920 * 2];
    static bool init = false;
    if (!init) {
        for (int k = 1; k < 16; ++k)
            for (int l = 0; l < 64; ++l) {
                double a = -2.0 * M_PI * (double)(k * l) / 1024.0;
                host_tw[2*((k-1)*64 + l) + 0] = (float)cos(a);
                host_tw[2*((k-1)*64 + l) + 1] = (float)sin(a);
            }
        for (int k = 1; k < 16; ++k)
            for (int l = 0; l < 64; ++l) {
                double a = -2.0 * M_PI * (double)(k * (l >> 4)) / 64.0;
                host_tw[2*(960 + (k-1)*64 + l) + 0] = (float)cos(a);
                host_tw[2*(960 + (k-1)*64 + l) + 1] = (float)sin(a);
            }
        init = true;
    }
    hipMemcpyAsync(d_ws, host_tw, sizeof(host_tw), hipMemcpyHostToDevice, stream);
    dim3 grid(512 * NBATCH, 1, 1);             // 8192 blocks, xcd-swizzled in-kernel
    stft_mag_kernel<<<grid, 256, 0, stream>>>(in, out, (const cplx*)d_ws);
}